// Round 1
// baseline (3793.034 us; speedup 1.0000x reference)
//
#include <hip/hip_runtime.h>

#define GLOBAL_AS __attribute__((address_space(1)))
#define LDS_AS __attribute__((address_space(3)))

typedef __attribute__((ext_vector_type(8))) __bf16 bf16x8;
typedef __attribute__((ext_vector_type(4))) float f32x4;

__device__ __forceinline__ unsigned short f2bf(float f) {
    union { float f; unsigned int u; } v; v.f = f;
    unsigned int r = v.u + 0x7fffu + ((v.u >> 16) & 1u);   // RNE
    return (unsigned short)(r >> 16);
}
__device__ __forceinline__ float bf2f(unsigned short s) {
    union { unsigned int u; float f; } v; v.u = ((unsigned int)s) << 16;
    return v.f;
}
__device__ __forceinline__ void async_copy16(const void* gp, void* lp) {
    __builtin_amdgcn_global_load_lds((GLOBAL_AS void*)const_cast<void*>(gp),
                                     (LDS_AS void*)lp, 16, 0, 0);
}

// ---------------- row sums: xm_sum[b] = sum_d x[b,d] ----------------
__global__ __launch_bounds__(256) void rowsum_kernel(const float* __restrict__ x,
                                                     float* __restrict__ xsum) {
    const int b = blockIdx.x, t = threadIdx.x;
    const float4* p = (const float4*)(x + (long)b * 4096);
    float s = 0.f;
#pragma unroll
    for (int i = 0; i < 4; ++i) {
        float4 v = p[t + 256 * i];
        s += v.x + v.y + v.z + v.w;
    }
#pragma unroll
    for (int m = 1; m < 64; m <<= 1) s += __shfl_xor(s, m, 64);
    __shared__ float ws4[4];
    if ((t & 63) == 0) ws4[t >> 6] = s;
    __syncthreads();
    if (t == 0) xsum[b] = ws4[0] + ws4[1] + ws4[2] + ws4[3];
}

// ---------------- col sums: ym_sum[d] = sum_b x[b,d] ----------------
__global__ __launch_bounds__(256) void colsum_kernel(const float* __restrict__ x,
                                                     float* __restrict__ ysum) {
    const int t = threadIdx.x;
    const int c0 = blockIdx.x * 1024 + t * 4;   // gridDim.x = 4
    const long r0 = (long)blockIdx.y * 256;     // gridDim.y = 64
    const float* p = x + r0 * 4096 + c0;
    float4 acc = {0.f, 0.f, 0.f, 0.f};
    for (int r = 0; r < 256; ++r) {
        float4 v = *(const float4*)p;
        acc.x += v.x; acc.y += v.y; acc.z += v.z; acc.w += v.w;
        p += 4096;
    }
    atomicAdd(&ysum[c0 + 0], acc.x);
    atomicAdd(&ysum[c0 + 1], acc.y);
    atomicAdd(&ysum[c0 + 2], acc.z);
    atomicAdd(&ysum[c0 + 3], acc.w);
}

// ---- gate: v = w*(sum*invCount)+b ; z=(v-mean)/(sqrt(var+eps)+eps); out=sigmoid(z)
__global__ __launch_bounds__(1024) void gate_kernel(const float* __restrict__ sums, int n,
                                                    float invCount,
                                                    const float* __restrict__ wp,
                                                    const float* __restrict__ bp,
                                                    float* __restrict__ out) {
    const int t = threadIdx.x;
    const float w = *wp, bb = *bp;
    float s = 0.f, s2 = 0.f;
    for (int i = t; i < n; i += 1024) {
        float v = w * (sums[i] * invCount) + bb;
        s += v; s2 += v * v;
    }
#pragma unroll
    for (int m = 1; m < 64; m <<= 1) { s += __shfl_xor(s, m, 64); s2 += __shfl_xor(s2, m, 64); }
    __shared__ float as1[16], as2[16];
    if ((t & 63) == 0) { as1[t >> 6] = s; as2[t >> 6] = s2; }
    __syncthreads();
    __shared__ float smu, sden;
    if (t == 0) {
        float S = 0.f, S2 = 0.f;
        for (int i = 0; i < 16; ++i) { S += as1[i]; S2 += as2[i]; }
        float mu = S / n;
        float var = S2 / n - mu * mu;
        smu = mu; sden = sqrtf(var + 1e-5f) + 1e-5f;
    }
    __syncthreads();
    const float mu = smu, den = sden;
    for (int i = t; i < n; i += 1024) {
        float v = w * (sums[i] * invCount) + bb;
        float z = (v - mu) / den;
        out[i] = 1.f / (1.f + expf(-z));
    }
}

// ---------------- g = x * gx[b] * gy[d]  -> bf16 ----------------
__global__ __launch_bounds__(256) void gmul_kernel(const float* __restrict__ x,
                                                   const float* __restrict__ gx,
                                                   const float* __restrict__ gy,
                                                   unsigned short* __restrict__ g) {
    long idx = ((long)blockIdx.x * 256 + threadIdx.x) * 8;
    int b = (int)(idx >> 12);
    int d = (int)(idx & 4095);
    float s = gx[b];
    float4 x0 = *(const float4*)(x + idx);
    float4 x1 = *(const float4*)(x + idx + 4);
    float4 g0 = *(const float4*)(gy + d);
    float4 g1 = *(const float4*)(gy + d + 4);
    union { unsigned short u[8]; uint4 v; } o;
    o.u[0] = f2bf(x0.x * s * g0.x); o.u[1] = f2bf(x0.y * s * g0.y);
    o.u[2] = f2bf(x0.z * s * g0.z); o.u[3] = f2bf(x0.w * s * g0.w);
    o.u[4] = f2bf(x1.x * s * g1.x); o.u[5] = f2bf(x1.y * s * g1.y);
    o.u[6] = f2bf(x1.z * s * g1.z); o.u[7] = f2bf(x1.w * s * g1.w);
    *(uint4*)(g + idx) = o.v;
}

// ---------------- fp32 -> bf16 weight convert ----------------
__global__ __launch_bounds__(256) void wconv_kernel(const float* __restrict__ src,
                                                    unsigned short* __restrict__ dst, long n) {
    long idx = ((long)blockIdx.x * 256 + threadIdx.x) * 8;
    if (idx >= n) return;
    float4 a = *(const float4*)(src + idx);
    float4 b = *(const float4*)(src + idx + 4);
    union { unsigned short u[8]; uint4 v; } o;
    o.u[0] = f2bf(a.x); o.u[1] = f2bf(a.y); o.u[2] = f2bf(a.z); o.u[3] = f2bf(a.w);
    o.u[4] = f2bf(b.x); o.u[5] = f2bf(b.y); o.u[6] = f2bf(b.z); o.u[7] = f2bf(b.w);
    *(uint4*)(dst + idx) = o.v;
}

// ---------------- GEMM: C[M,N] = A[M,K] * Bw[N,K]^T + bias ----------------
// m97 structure: 128x128 tile, BK=64, 4 waves (2x2), each wave 4x4 of 16x16x32 bf16 MFMA.
// global_load_lds width=16; LDS column-group XOR-swizzled by (row&7) on the GLOBAL
// address side (scatter is lane-contiguous, so swizzle must be baked into which
// element each lane fetches). Read side applies the same XOR -> conflict-free-ish.
template <bool OUT_BF16>
__global__ __launch_bounds__(256) void gemm_bt(const unsigned short* __restrict__ A,
                                               const unsigned short* __restrict__ Bw,
                                               const float* __restrict__ bias,
                                               void* __restrict__ Cp,
                                               int M, int N, int K) {
    constexpr int BK = 64;
    __shared__ unsigned short lA[128 * BK];
    __shared__ unsigned short lB[128 * BK];
    const int tid = threadIdx.x;
    const int wave = tid >> 6;
    const int lane = tid & 63;
    const long bm = (long)blockIdx.y * 128;
    const long bn = (long)blockIdx.x * 128;
    const int wm = (wave >> 1) * 64;
    const int wn = (wave & 1) * 64;
    const int srow = lane >> 3;               // 0..7 within 8-row chunk
    const int sg = (lane & 7) ^ srow;         // swizzled 16B col-group this lane fetches
    const int quad = lane >> 4;
    const int lr = lane & 15;

    const unsigned short* Ag = A + (bm + wave * 32 + srow) * (long)K + sg * 8;
    const unsigned short* Bg = Bw + (bn + wave * 32 + srow) * (long)K + sg * 8;
    unsigned short* lAw = lA + (wave * 4) * 512;
    unsigned short* lBw = lB + (wave * 4) * 512;

    const f32x4 fzero = {0.f, 0.f, 0.f, 0.f};
    f32x4 acc[4][4];
#pragma unroll
    for (int i = 0; i < 4; ++i)
#pragma unroll
        for (int j = 0; j < 4; ++j) acc[i][j] = fzero;

    for (int k0 = 0; k0 < K; k0 += BK) {
#pragma unroll
        for (int i = 0; i < 4; ++i) {
            async_copy16(Ag + (long)i * 8 * K + k0, lAw + i * 512);
            async_copy16(Bg + (long)i * 8 * K + k0, lBw + i * 512);
        }
        __syncthreads();   // compiler emits vmcnt(0) drain before barrier
#pragma unroll
        for (int kk = 0; kk < BK; kk += 32) {
            const int gb = kk >> 3;   // 0 or 4
            bf16x8 af[4], bfr[4];
#pragma unroll
            for (int mt = 0; mt < 4; ++mt) {
                int r = wm + mt * 16 + lr;
                af[mt] = *(const bf16x8*)&lA[r * 64 + (((gb + quad) ^ (r & 7)) << 3)];
            }
#pragma unroll
            for (int nt = 0; nt < 4; ++nt) {
                int r = wn + nt * 16 + lr;
                bfr[nt] = *(const bf16x8*)&lB[r * 64 + (((gb + quad) ^ (r & 7)) << 3)];
            }
#pragma unroll
            for (int mt = 0; mt < 4; ++mt)
#pragma unroll
                for (int nt = 0; nt < 4; ++nt)
                    acc[mt][nt] = __builtin_amdgcn_mfma_f32_16x16x32_bf16(
                        af[mt], bfr[nt], acc[mt][nt], 0, 0, 0);
        }
        __syncthreads();
    }

    // epilogue: C/D layout col=lane&15, row=quad*4+reg (m89/m91-verified)
#pragma unroll
    for (int nt = 0; nt < 4; ++nt) {
        long col = bn + wn + nt * 16 + lr;
        float bv = bias[col];
#pragma unroll
        for (int mt = 0; mt < 4; ++mt) {
#pragma unroll
            for (int r = 0; r < 4; ++r) {
                long row = bm + wm + mt * 16 + quad * 4 + r;
                float v = acc[mt][nt][r] + bv;
                if (OUT_BF16)
                    ((unsigned short*)Cp)[row * (long)N + col] = f2bf(v);
                else
                    ((float*)Cp)[row * (long)N + col] = v;
            }
        }
    }
}

// ------- per-row: scores -> softmax over 32 heads -> attn+g -> LayerNorm -> bf16 -------
__global__ __launch_bounds__(256) void attn_ln_kernel(const unsigned short* __restrict__ qkv,
                                                      const unsigned short* __restrict__ g,
                                                      const float* __restrict__ gamma,
                                                      const float* __restrict__ beta,
                                                      unsigned short* __restrict__ hout) {
    const int b = blockIdx.x, t = threadIdx.x;
    const unsigned short* Qr = qkv + (long)b * 12288;
    const unsigned short* Kr = Qr + 4096;
    const unsigned short* Vr = Qr + 8192;
    const unsigned short* gr = g + (long)b * 4096;

    __shared__ float sw[32];
    {   // per-head scalar dot: 8 threads/head, 16 elements each
        int head = t >> 3, j = t & 7;
        int base = head * 128 + j;
        float acc = 0.f;
#pragma unroll
        for (int i = 0; i < 16; ++i) {
            int d = base + i * 8;
            acc += bf2f(Qr[d]) * bf2f(Kr[d]);
        }
        acc += __shfl_xor(acc, 1, 64);
        acc += __shfl_xor(acc, 2, 64);
        acc += __shfl_xor(acc, 4, 64);
        if (j == 0) sw[head] = acc * 0.0883883476483184f;   // 1/sqrt(128)
    }
    __syncthreads();
    if (t < 32) {   // softmax over heads (wave0 lanes 0..31, lockstep)
        float s = sw[t];
        float mx = s;
#pragma unroll
        for (int m = 1; m < 32; m <<= 1) mx = fmaxf(mx, __shfl_xor(mx, m, 64));
        float e = expf(s - mx);
        float sum = e;
#pragma unroll
        for (int m = 1; m < 32; m <<= 1) sum += __shfl_xor(sum, m, 64);
        sw[t] = e / sum;
    }
    __syncthreads();

    float y[16];
    float s = 0.f, s2 = 0.f;
#pragma unroll
    for (int i = 0; i < 16; ++i) {
        int d = t + 256 * i;
        float v = sw[d >> 7] * bf2f(Vr[d]) + bf2f(gr[d]);
        y[i] = v; s += v; s2 += v * v;
    }
#pragma unroll
    for (int m = 1; m < 64; m <<= 1) { s += __shfl_xor(s, m, 64); s2 += __shfl_xor(s2, m, 64); }
    __shared__ float rs[4], rs2[4];
    if ((t & 63) == 0) { rs[t >> 6] = s; rs2[t >> 6] = s2; }
    __syncthreads();
    float S = rs[0] + rs[1] + rs[2] + rs[3];
    float S2 = rs2[0] + rs2[1] + rs2[2] + rs2[3];
    float mu = S * (1.f / 4096.f);
    float var = S2 * (1.f / 4096.f) - mu * mu;
    float rstd = rsqrtf(var + 1e-5f);
    unsigned short* ho = hout + (long)b * 4096;
#pragma unroll
    for (int i = 0; i < 16; ++i) {
        int d = t + 256 * i;
        float v = (y[i] - mu) * rstd * gamma[d] + beta[d];
        ho[d] = f2bf(v);   // safe even when hout aliases g: same thread, same index
    }
}

extern "C" void kernel_launch(void* const* d_in, const int* in_sizes, int n_in,
                              void* d_out, int out_size, void* d_ws, size_t ws_size,
                              hipStream_t stream) {
    const float* x  = (const float*)d_in[0];
    const float* wx = (const float*)d_in[1];
    const float* bx = (const float*)d_in[2];
    const float* wy = (const float*)d_in[3];
    const float* by = (const float*)d_in[4];
    const float* Wq = (const float*)d_in[5];
    const float* bq = (const float*)d_in[6];
    const float* Wk = (const float*)d_in[7];
    const float* bk = (const float*)d_in[8];
    const float* Wv = (const float*)d_in[9];
    const float* bv = (const float*)d_in[10];
    const float* Wo = (const float*)d_in[11];
    const float* bo = (const float*)d_in[12];
    const float* gamma = (const float*)d_in[13];
    const float* beta  = (const float*)d_in[14];

    const long B = 16384, D = 4096;
    const long DD = D * D;

    char* w = (char*)d_ws;
    auto alloc = [&](size_t bytes) {
        char* p = w;
        w += (bytes + 255) & ~(size_t)255;
        return p;
    };
    unsigned short* gbf  = (unsigned short*)alloc(B * D * 2);      // g (bf16); reused as h
    unsigned short* wqkv = (unsigned short*)alloc(3 * DD * 2);     // [Wq;Wk;Wv] bf16
    unsigned short* wobf = (unsigned short*)alloc(DD * 2);         // Wo bf16
    unsigned short* qkvb = (unsigned short*)alloc(B * 3 * D * 2);  // QKV bf16
    float* xsum = (float*)alloc(B * 4);
    float* ysum = (float*)alloc(D * 4);
    float* gx   = (float*)alloc(B * 4);
    float* gy   = (float*)alloc(D * 4);
    float* bqkv = (float*)alloc(3 * D * 4);

    hipMemsetAsync(ysum, 0, D * sizeof(float), stream);

    rowsum_kernel<<<dim3(16384), dim3(256), 0, stream>>>(x, xsum);
    colsum_kernel<<<dim3(4, 64), dim3(256), 0, stream>>>(x, ysum);
    gate_kernel<<<dim3(1), dim3(1024), 0, stream>>>(xsum, 16384, 1.f / 4096.f, wx, bx, gx);
    gate_kernel<<<dim3(1), dim3(1024), 0, stream>>>(ysum, 4096, 1.f / 16384.f, wy, by, gy);
    gmul_kernel<<<dim3(32768), dim3(256), 0, stream>>>(x, gx, gy, gbf);

    wconv_kernel<<<dim3(8192), dim3(256), 0, stream>>>(Wq, wqkv, DD);
    wconv_kernel<<<dim3(8192), dim3(256), 0, stream>>>(Wk, wqkv + DD, DD);
    wconv_kernel<<<dim3(8192), dim3(256), 0, stream>>>(Wv, wqkv + 2 * DD, DD);
    wconv_kernel<<<dim3(8192), dim3(256), 0, stream>>>(Wo, wobf, DD);
    hipMemcpyAsync(bqkv, bq, D * sizeof(float), hipMemcpyDeviceToDevice, stream);
    hipMemcpyAsync(bqkv + D, bk, D * sizeof(float), hipMemcpyDeviceToDevice, stream);
    hipMemcpyAsync(bqkv + 2 * D, bv, D * sizeof(float), hipMemcpyDeviceToDevice, stream);

    // QKV fused GEMM: [16384,4096] x [12288,4096]^T -> bf16 [16384,12288]
    gemm_bt<true><<<dim3(96, 128), dim3(256), 0, stream>>>(gbf, wqkv, bqkv, qkvb,
                                                           16384, 12288, 4096);
    // attention + residual + LayerNorm -> h (bf16), written over gbf
    attn_ln_kernel<<<dim3(16384), dim3(256), 0, stream>>>(qkvb, gbf, gamma, beta, gbf);
    // out = h @ Wo^T + bo -> fp32
    gemm_bt<false><<<dim3(32, 128), dim3(256), 0, stream>>>(gbf, wobf, bo, (float*)d_out,
                                                            16384, 4096, 4096);
    (void)in_sizes; (void)n_in; (void)out_size; (void)ws_size;
}